// Round 5
// baseline (477.755 us; speedup 1.0000x reference)
//
#include <hip/hip_runtime.h>
#include <hip/hip_bf16.h>
#include <stdint.h>

// B=1, S=4096, D=1024, H=16, HD=64. I/O = float32; internal compute bf16 MFMA.
constexpr int SEQ  = 4096;
constexpr int DIM  = 1024;
constexpr int NH   = 16;
constexpr int HDM  = 64;

typedef __bf16 bf16;
typedef __attribute__((ext_vector_type(4)))  float  f32x4;
typedef __attribute__((ext_vector_type(16))) float  f32x16;
typedef __attribute__((ext_vector_type(8)))  __bf16 bf16x8;
typedef __attribute__((ext_vector_type(4)))  __bf16 bf16x4;
typedef __attribute__((ext_vector_type(4)))  unsigned u32x4;

__device__ __forceinline__ void gload_lds16(const bf16* g, bf16* l) {
  __builtin_amdgcn_global_load_lds(
      (const __attribute__((address_space(1))) unsigned int*)g,
      (__attribute__((address_space(3))) unsigned int*)l, 16, 0, 0);
}

__device__ __forceinline__ unsigned pack2(float lo, float hi) {
  unsigned short a = __builtin_bit_cast(unsigned short, (bf16)lo);
  unsigned short b = __builtin_bit_cast(unsigned short, (bf16)hi);
  return ((unsigned)b << 16) | a;
}

// f32 -> bf16 for x + the 4 weight matrices. blockIdx.y selects tensor.
__global__ void cvt5(const float* __restrict__ x,  const float* __restrict__ wq,
                     const float* __restrict__ wk, const float* __restrict__ wv,
                     const float* __restrict__ wo,
                     bf16* __restrict__ xb,  bf16* __restrict__ wqb,
                     bf16* __restrict__ wkb, bf16* __restrict__ wvb,
                     bf16* __restrict__ wob) {
  const float* in; bf16* out; int n;
  switch (blockIdx.y) {
    case 0:  in = x;  out = xb;  n = SEQ * DIM; break;
    case 1:  in = wq; out = wqb; n = DIM * DIM; break;
    case 2:  in = wk; out = wkb; n = DIM * DIM; break;
    case 3:  in = wv; out = wvb; n = DIM * DIM; break;
    default: in = wo; out = wob; n = DIM * DIM; break;
  }
  const int i = (blockIdx.x * blockDim.x + threadIdx.x) * 8;
  if (i >= n) return;
  f32x4 a = *(const f32x4*)(in + i);
  f32x4 b = *(const f32x4*)(in + i + 4);
  bf16x8 o;
#pragma unroll
  for (int j = 0; j < 4; ++j) { o[j] = (bf16)a[j]; o[j + 4] = (bf16)b[j]; }
  *(bf16x8*)(out + i) = o;
}

// ---------------- GEMM: C = A[rows][1024] * W[1024][1024]^T ----------------
template <typename OutT, bool QKV>
__global__ __launch_bounds__(256, 2)
void gemm_xwt(const bf16* __restrict__ A,
              const bf16* __restrict__ W0, const bf16* __restrict__ W1,
              const bf16* __restrict__ W2,
              OutT* __restrict__ C0, OutT* __restrict__ C1, OutT* __restrict__ C2) {
  const bf16* W;
  OutT* C;
  if (QKV) {
    const int z = blockIdx.z;
    W = (z == 0) ? W0 : (z == 1) ? W1 : W2;
    C = (z == 0) ? C0 : (z == 1) ? C1 : C2;
  } else {
    W = W0; C = C0;
  }
  __shared__ bf16 As[128 * 32];
  __shared__ bf16 Bs[128 * 32];
  const int tid = threadIdx.x;
  const int w   = tid >> 6;
  const int l   = tid & 63;
  const int l15 = l & 15, lhi = l >> 4;
  const int wr  = w >> 1, wc = w & 1;
  const int row0 = blockIdx.y * 128;
  const int col0 = blockIdx.x * 128;

  f32x4 acc[4][4] = {};

  const int srow = w * 32 + (l >> 2);
  const int scol = (l & 3) * 8;
  const bf16* gA = A + (size_t)(row0 + srow) * DIM + scol;
  const bf16* gB = W + (size_t)(col0 + srow) * DIM + scol;
  bf16* lA = As + srow * 32 + scol;
  bf16* lB = Bs + srow * 32 + scol;

  for (int k0 = 0; k0 < DIM; k0 += 32) {
    __syncthreads();
    gload_lds16(gA + k0,            lA);
    gload_lds16(gA + k0 + 16 * DIM, lA + 16 * 32);
    gload_lds16(gB + k0,            lB);
    gload_lds16(gB + k0 + 16 * DIM, lB + 16 * 32);
    __syncthreads();
    bf16x8 af[4], bf_[4];
#pragma unroll
    for (int m = 0; m < 4; ++m)
      af[m] = *(const bf16x8*)(As + (wr * 64 + m * 16 + l15) * 32 + lhi * 8);
#pragma unroll
    for (int n = 0; n < 4; ++n)
      bf_[n] = *(const bf16x8*)(Bs + (wc * 64 + n * 16 + l15) * 32 + lhi * 8);
#pragma unroll
    for (int m = 0; m < 4; ++m)
#pragma unroll
      for (int n = 0; n < 4; ++n)
        acc[m][n] = __builtin_amdgcn_mfma_f32_16x16x32_bf16(af[m], bf_[n], acc[m][n], 0, 0, 0);
  }

#pragma unroll
  for (int m = 0; m < 4; ++m)
#pragma unroll
    for (int n = 0; n < 4; ++n)
#pragma unroll
      for (int r = 0; r < 4; ++r) {
        const int row = row0 + wr * 64 + m * 16 + lhi * 4 + r;
        const int col = col0 + wc * 64 + n * 16 + l15;
        C[(size_t)row * DIM + col] = (OutT)acc[m][n][r];
      }
}

// --------------- V transpose: Vt[d][s] = Vs[s][d]  (once) -------------------
__global__ __launch_bounds__(256)
void transpose_v(const bf16* __restrict__ Vs, bf16* __restrict__ Vt) {
  __shared__ bf16 t[64][72];
  const int st = blockIdx.x * 64;
  const int dt = blockIdx.y * 64;
  const int tid = threadIdx.x;
  const int r  = tid >> 2;
  const int c0 = (tid & 3) * 16;
  bf16x8 a = *(const bf16x8*)(Vs + (size_t)(st + r) * DIM + dt + c0);
  bf16x8 b = *(const bf16x8*)(Vs + (size_t)(st + r) * DIM + dt + c0 + 8);
#pragma unroll
  for (int j = 0; j < 8; ++j) { t[r][c0 + j] = a[j]; t[r][c0 + 8 + j] = b[j]; }
  __syncthreads();
  const int d  = tid >> 2;
  const int s0 = (tid & 3) * 16;
  bf16x8 o1, o2;
#pragma unroll
  for (int j = 0; j < 8; ++j) { o1[j] = t[s0 + j][d]; o2[j] = t[s0 + 8 + j][d]; }
  bf16* dst = Vt + (size_t)(dt + d) * SEQ + st + s0;
  *(bf16x8*)(dst)     = o1;
  *(bf16x8*)(dst + 8) = o2;
}

// ------- Causal flash attention, swapped-operand 32x32, 4-way split-K -------
// Block = 4 waves, one 32-row q-tile. Wave g does KV tiles t = g, g+4, ...
// with private online (m, sum, O^T); LDS flash-combine at the end.
__global__ __launch_bounds__(256, 4)
void attn_fwd(const bf16* __restrict__ Qg, const bf16* __restrict__ Kg,
              const bf16* __restrict__ Vt, bf16* __restrict__ Og) {
  __shared__ bf16  Plds[3][64][32];   // waves 1-3 O^T partials (bf16)
  __shared__ float Mlds[4][64];
  __shared__ float Slds[4][64];
  const int tid = threadIdx.x;
  const int wv  = tid >> 6;          // split-K group 0..3
  const int l   = tid & 63;
  const int l31 = l & 31;
  const int hi  = l >> 5;
  const int h   = blockIdx.x & 15;
  const int i   = 127 - (int)(blockIdx.x >> 4);  // big tiles dispatch first
  const int q0  = i * 32;
  const int hc  = h * HDM;
  const int tlast = i >> 1;
  const int qg  = q0 + l31;
  constexpr float C = 0.18033688011112042f;  // 0.125 * log2(e)

  // Q B-frags: lane holds Q[qg][hc + ks*16 + hi*8 ..+8)
  bf16x8 qf[4];
#pragma unroll
  for (int ks = 0; ks < 4; ++ks)
    qf[ks] = *(const bf16x8*)(Qg + (size_t)qg * DIM + hc + ks * 16 + hi * 8);

  f32x16 ot0 = {}, ot1 = {};          // O^T: d = (r&3)+8*(r>>2)+4*hi (+32)
  float m2 = -3.0e38f, sum_ = 0.f;

#pragma unroll 1
  for (int t = wv; t <= tlast; t += 4) {
    const int kv0 = t * 64;
    bf16x8 kf0[4], kf1[4];
#pragma unroll
    for (int ks = 0; ks < 4; ++ks) {
      kf0[ks] = *(const bf16x8*)(Kg + (size_t)(kv0 + l31) * DIM + hc + ks * 16 + hi * 8);
      kf1[ks] = *(const bf16x8*)(Kg + (size_t)(kv0 + 32 + l31) * DIM + hc + ks * 16 + hi * 8);
    }
    f32x16 s0 = {}, s1 = {};
#pragma unroll
    for (int ks = 0; ks < 4; ++ks) {
      s0 = __builtin_amdgcn_mfma_f32_32x32x16_bf16(kf0[ks], qf[ks], s0, 0, 0, 0);
      s1 = __builtin_amdgcn_mfma_f32_32x32x16_bf16(kf1[ks], qf[ks], s1, 0, 0, 0);
    }
    bf16x8 vf0[4], vf1[4];
#pragma unroll
    for (int k2 = 0; k2 < 4; ++k2) {
      vf0[k2] = *(const bf16x8*)(Vt + (size_t)(hc + l31) * SEQ + kv0 + k2 * 16 + hi * 8);
      vf1[k2] = *(const bf16x8*)(Vt + (size_t)(hc + 32 + l31) * SEQ + kv0 + k2 * 16 + hi * 8);
    }
    if (t == tlast) {
#pragma unroll
      for (int r = 0; r < 16; ++r) {
        const int kp = (r & 3) + 8 * (r >> 2) + 4 * hi;
        s0[r] = (kv0 + kp      > qg) ? -1.0e30f : s0[r] * C;
        s1[r] = (kv0 + 32 + kp > qg) ? -1.0e30f : s1[r] * C;
      }
    } else {
#pragma unroll
      for (int r = 0; r < 16; ++r) { s0[r] *= C; s1[r] *= C; }
    }
    // row max: depth-5 tree + 1 partner exchange
    float tm[8];
#pragma unroll
    for (int r = 0; r < 8; ++r)
      tm[r] = fmaxf(fmaxf(s0[r], s0[r + 8]), fmaxf(s1[r], s1[r + 8]));
#pragma unroll
    for (int d = 4; d >= 1; d >>= 1)
#pragma unroll
      for (int r = 0; r < d; ++r) tm[r] = fmaxf(tm[r], tm[r + d]);
    float pm = fmaxf(tm[0], __shfl_xor(tm[0], 32));
    const float mn = fmaxf(m2, pm);
    const float al = __builtin_exp2f(m2 - mn);
    m2 = mn;
    sum_ *= al;
#pragma unroll
    for (int r = 0; r < 16; ++r) { ot0[r] *= al; ot1[r] *= al; }
    float rs = 0.f;
#pragma unroll
    for (int r = 0; r < 16; ++r) {
      s0[r] = __builtin_exp2f(s0[r] - m2);
      s1[r] = __builtin_exp2f(s1[r] - m2);
      rs += s0[r] + s1[r];
    }
    sum_ += rs;
    // P^T B-frags via packed half-exchange with lane^32
#pragma unroll
    for (int sub = 0; sub < 2; ++sub) {
#pragma unroll
      for (int hf = 0; hf < 2; ++hf) {
        const int rb = hf * 8;
        float v0, v1, v2, v3, v4, v5, v6, v7;
        if (sub == 0) {
          v0 = s0[rb+0]; v1 = s0[rb+1]; v2 = s0[rb+2]; v3 = s0[rb+3];
          v4 = s0[rb+4]; v5 = s0[rb+5]; v6 = s0[rb+6]; v7 = s0[rb+7];
        } else {
          v0 = s1[rb+0]; v1 = s1[rb+1]; v2 = s1[rb+2]; v3 = s1[rb+3];
          v4 = s1[rb+4]; v5 = s1[rb+5]; v6 = s1[rb+6]; v7 = s1[rb+7];
        }
        const unsigned w0 = pack2(v0, v1), w1 = pack2(v2, v3);
        const unsigned w2 = pack2(v4, v5), w3 = pack2(v6, v7);
        const unsigned y0 = __shfl_xor((int)w0, 32), y1 = __shfl_xor((int)w1, 32);
        const unsigned y2 = __shfl_xor((int)w2, 32), y3 = __shfl_xor((int)w3, 32);
        u32x4 fu;
        fu[0] = hi ? y2 : w0;
        fu[1] = hi ? y3 : w1;
        fu[2] = hi ? w2 : y0;
        fu[3] = hi ? w3 : y1;
        const bf16x8 pb = __builtin_bit_cast(bf16x8, fu);
        const int k2 = sub * 2 + hf;
        ot0 = __builtin_amdgcn_mfma_f32_32x32x16_bf16(k2 == 0 ? vf0[0] : k2 == 1 ? vf0[1] : k2 == 2 ? vf0[2] : vf0[3], pb, ot0, 0, 0, 0);
        ot1 = __builtin_amdgcn_mfma_f32_32x32x16_bf16(k2 == 0 ? vf1[0] : k2 == 1 ? vf1[1] : k2 == 2 ? vf1[2] : vf1[3], pb, ot1, 0, 0, 0);
      }
    }
  }

  // spill partials
  Mlds[wv][l] = m2;
  Slds[wv][l] = sum_;
  if (wv) {
#pragma unroll
    for (int r = 0; r < 16; ++r) {
      Plds[wv - 1][l][r]      = (bf16)ot0[r];
      Plds[wv - 1][l][r + 16] = (bf16)ot1[r];
    }
  }
  __syncthreads();
  if (wv) return;

  // flash combine (wave 0)
  float mstar = m2;
#pragma unroll
  for (int w = 1; w < 4; ++w) mstar = fmaxf(mstar, Mlds[w][l]);
  float alw[4];
  alw[0] = __builtin_exp2f(m2 - mstar);
#pragma unroll
  for (int w = 1; w < 4; ++w) alw[w] = __builtin_exp2f(Mlds[w][l] - mstar);
  float den = 0.f;
#pragma unroll
  for (int w = 0; w < 4; ++w)
    den += (Slds[w][l] + Slds[w][l ^ 32]) * alw[w];
  float num0[16], num1[16];
#pragma unroll
  for (int r = 0; r < 16; ++r) { num0[r] = ot0[r] * alw[0]; num1[r] = ot1[r] * alw[0]; }
#pragma unroll
  for (int w = 1; w < 4; ++w) {
    bf16x8 p0 = *(const bf16x8*)(&Plds[w - 1][l][0]);
    bf16x8 p1 = *(const bf16x8*)(&Plds[w - 1][l][8]);
    bf16x8 p2 = *(const bf16x8*)(&Plds[w - 1][l][16]);
    bf16x8 p3 = *(const bf16x8*)(&Plds[w - 1][l][24]);
#pragma unroll
    for (int e = 0; e < 8; ++e) {
      num0[e]     += (float)p0[e] * alw[w];
      num0[e + 8] += (float)p1[e] * alw[w];
      num1[e]     += (float)p2[e] * alw[w];
      num1[e + 8] += (float)p3[e] * alw[w];
    }
  }
  const float inv = 1.0f / den;
#pragma unroll
  for (int g = 0; g < 4; ++g) {
    bf16x4 o0, o1;
#pragma unroll
    for (int e = 0; e < 4; ++e) {
      o0[e] = (bf16)(num0[g * 4 + e] * inv);
      o1[e] = (bf16)(num1[g * 4 + e] * inv);
    }
    *(bf16x4*)(Og + (size_t)qg * DIM + hc + g * 8 + hi * 4)      = o0;
    *(bf16x4*)(Og + (size_t)qg * DIM + hc + 32 + g * 8 + hi * 4) = o1;
  }
}

extern "C" void kernel_launch(void* const* d_in, const int* in_sizes, int n_in,
                              void* d_out, int out_size, void* d_ws, size_t ws_size,
                              hipStream_t stream) {
  const float* x  = (const float*)d_in[0];
  const float* Wq = (const float*)d_in[1];
  const float* Wk = (const float*)d_in[2];
  const float* Wv = (const float*)d_in[3];
  const float* Wo = (const float*)d_in[4];
  float* out = (float*)d_out;

  // ws (bf16, 48MB): xb 8MB | Wq..Wo 2MB each | Q,K,V 8MB each
  // aliases: Vt <- xb (xb dead after QKV gemm); At <- Vs (Vs dead after transpose)
  bf16* xb  = (bf16*)d_ws;
  bf16* wqb = xb  + (size_t)SEQ * DIM;
  bf16* wkb = wqb + (size_t)DIM * DIM;
  bf16* wvb = wkb + (size_t)DIM * DIM;
  bf16* wob = wvb + (size_t)DIM * DIM;
  bf16* Qs  = wob + (size_t)DIM * DIM;
  bf16* Ks  = Qs  + (size_t)SEQ * DIM;
  bf16* Vs  = Ks  + (size_t)SEQ * DIM;
  bf16* Vt  = xb;   // [DIM][SEQ]
  bf16* At  = Vs;

  cvt5<<<dim3((SEQ * DIM) / (256 * 8), 5), 256, 0, stream>>>(
      x, Wq, Wk, Wv, Wo, xb, wqb, wkb, wvb, wob);

  gemm_xwt<bf16, true><<<dim3(DIM / 128, SEQ / 128, 3), 256, 0, stream>>>(
      xb, wqb, wkb, wvb, Qs, Ks, Vs);

  transpose_v<<<dim3(SEQ / 64, DIM / 64), 256, 0, stream>>>(Vs, Vt);

  attn_fwd<<<dim3(128 * NH), 256, 0, stream>>>(Qs, Ks, Vt, At);

  gemm_xwt<float, false><<<dim3(DIM / 128, SEQ / 128), 256, 0, stream>>>(
      At, wob, nullptr, nullptr, out, nullptr, nullptr);
}

// Round 6
// 205.928 us; speedup vs baseline: 2.3200x; 2.3200x over previous
//
#include <hip/hip_runtime.h>
#include <hip/hip_bf16.h>
#include <stdint.h>

// B=1, S=4096, D=1024, H=16, HD=64. I/O = float32; internal compute bf16 MFMA.
constexpr int SEQ  = 4096;
constexpr int DIM  = 1024;
constexpr int NH   = 16;
constexpr int HDM  = 64;

typedef __bf16 bf16;
typedef __attribute__((ext_vector_type(4)))  float  f32x4;
typedef __attribute__((ext_vector_type(16))) float  f32x16;
typedef __attribute__((ext_vector_type(8)))  __bf16 bf16x8;
typedef __attribute__((ext_vector_type(4)))  __bf16 bf16x4;
typedef __attribute__((ext_vector_type(4)))  unsigned u32x4;

__device__ __forceinline__ void gload_lds16(const bf16* g, bf16* l) {
  __builtin_amdgcn_global_load_lds(
      (const __attribute__((address_space(1))) unsigned int*)g,
      (__attribute__((address_space(3))) unsigned int*)l, 16, 0, 0);
}

__device__ __forceinline__ unsigned pack2(float lo, float hi) {
  unsigned short a = __builtin_bit_cast(unsigned short, (bf16)lo);
  unsigned short b = __builtin_bit_cast(unsigned short, (bf16)hi);
  return ((unsigned)b << 16) | a;
}

// f32 -> bf16 for x + the 4 weight matrices. blockIdx.y selects tensor.
__global__ void cvt5(const float* __restrict__ x,  const float* __restrict__ wq,
                     const float* __restrict__ wk, const float* __restrict__ wv,
                     const float* __restrict__ wo,
                     bf16* __restrict__ xb,  bf16* __restrict__ wqb,
                     bf16* __restrict__ wkb, bf16* __restrict__ wvb,
                     bf16* __restrict__ wob) {
  const float* in; bf16* out; int n;
  switch (blockIdx.y) {
    case 0:  in = x;  out = xb;  n = SEQ * DIM; break;
    case 1:  in = wq; out = wqb; n = DIM * DIM; break;
    case 2:  in = wk; out = wkb; n = DIM * DIM; break;
    case 3:  in = wv; out = wvb; n = DIM * DIM; break;
    default: in = wo; out = wob; n = DIM * DIM; break;
  }
  const int i = (blockIdx.x * blockDim.x + threadIdx.x) * 8;
  if (i >= n) return;
  f32x4 a = *(const f32x4*)(in + i);
  f32x4 b = *(const f32x4*)(in + i + 4);
  bf16x8 o;
#pragma unroll
  for (int j = 0; j < 4; ++j) { o[j] = (bf16)a[j]; o[j + 4] = (bf16)b[j]; }
  *(bf16x8*)(out + i) = o;
}

// ---------------- GEMM: C = A[rows][1024] * W[1024][1024]^T ----------------
template <typename OutT, bool QKV>
__global__ __launch_bounds__(256, 2)
void gemm_xwt(const bf16* __restrict__ A,
              const bf16* __restrict__ W0, const bf16* __restrict__ W1,
              const bf16* __restrict__ W2,
              OutT* __restrict__ C0, OutT* __restrict__ C1, OutT* __restrict__ C2) {
  const bf16* W;
  OutT* C;
  if (QKV) {
    const int z = blockIdx.z;
    W = (z == 0) ? W0 : (z == 1) ? W1 : W2;
    C = (z == 0) ? C0 : (z == 1) ? C1 : C2;
  } else {
    W = W0; C = C0;
  }
  __shared__ bf16 As[128 * 32];
  __shared__ bf16 Bs[128 * 32];
  const int tid = threadIdx.x;
  const int w   = tid >> 6;
  const int l   = tid & 63;
  const int l15 = l & 15, lhi = l >> 4;
  const int wr  = w >> 1, wc = w & 1;
  const int row0 = blockIdx.y * 128;
  const int col0 = blockIdx.x * 128;

  f32x4 acc[4][4] = {};

  const int srow = w * 32 + (l >> 2);
  const int scol = (l & 3) * 8;
  const bf16* gA = A + (size_t)(row0 + srow) * DIM + scol;
  const bf16* gB = W + (size_t)(col0 + srow) * DIM + scol;
  bf16* lA = As + srow * 32 + scol;
  bf16* lB = Bs + srow * 32 + scol;

  for (int k0 = 0; k0 < DIM; k0 += 32) {
    __syncthreads();
    gload_lds16(gA + k0,            lA);
    gload_lds16(gA + k0 + 16 * DIM, lA + 16 * 32);
    gload_lds16(gB + k0,            lB);
    gload_lds16(gB + k0 + 16 * DIM, lB + 16 * 32);
    __syncthreads();
    bf16x8 af[4], bf_[4];
#pragma unroll
    for (int m = 0; m < 4; ++m)
      af[m] = *(const bf16x8*)(As + (wr * 64 + m * 16 + l15) * 32 + lhi * 8);
#pragma unroll
    for (int n = 0; n < 4; ++n)
      bf_[n] = *(const bf16x8*)(Bs + (wc * 64 + n * 16 + l15) * 32 + lhi * 8);
#pragma unroll
    for (int m = 0; m < 4; ++m)
#pragma unroll
      for (int n = 0; n < 4; ++n)
        acc[m][n] = __builtin_amdgcn_mfma_f32_16x16x32_bf16(af[m], bf_[n], acc[m][n], 0, 0, 0);
  }

#pragma unroll
  for (int m = 0; m < 4; ++m)
#pragma unroll
    for (int n = 0; n < 4; ++n)
#pragma unroll
      for (int r = 0; r < 4; ++r) {
        const int row = row0 + wr * 64 + m * 16 + lhi * 4 + r;
        const int col = col0 + wc * 64 + n * 16 + l15;
        C[(size_t)row * DIM + col] = (OutT)acc[m][n][r];
      }
}

// --------------- V transpose: Vt[d][s] = Vs[s][d]  (once) -------------------
__global__ __launch_bounds__(256)
void transpose_v(const bf16* __restrict__ Vs, bf16* __restrict__ Vt) {
  __shared__ bf16 t[64][72];
  const int st = blockIdx.x * 64;
  const int dt = blockIdx.y * 64;
  const int tid = threadIdx.x;
  const int r  = tid >> 2;
  const int c0 = (tid & 3) * 16;
  bf16x8 a = *(const bf16x8*)(Vs + (size_t)(st + r) * DIM + dt + c0);
  bf16x8 b = *(const bf16x8*)(Vs + (size_t)(st + r) * DIM + dt + c0 + 8);
#pragma unroll
  for (int j = 0; j < 8; ++j) { t[r][c0 + j] = a[j]; t[r][c0 + 8 + j] = b[j]; }
  __syncthreads();
  const int d  = tid >> 2;
  const int s0 = (tid & 3) * 16;
  bf16x8 o1, o2;
#pragma unroll
  for (int j = 0; j < 8; ++j) { o1[j] = t[s0 + j][d]; o2[j] = t[s0 + 8 + j][d]; }
  bf16* dst = Vt + (size_t)(dt + d) * SEQ + st + s0;
  *(bf16x8*)(dst)     = o1;
  *(bf16x8*)(dst + 8) = o2;
}

// ------- Causal flash attention, swapped-operand 32x32, 4-way split-K -------
// Block = 4 waves, one 32-row q-tile. Wave g does KV tiles t = g, g+4, ...
// with private online (m, sum, O^T); LDS flash-combine at the end.
// launch_bounds(256,2): cap 256 VGPR — (256,4) forced 64 VGPR and spilled
// 1.3 GB/dispatch to scratch (round-5 regression).
__global__ __launch_bounds__(256, 2)
void attn_fwd(const bf16* __restrict__ Qg, const bf16* __restrict__ Kg,
              const bf16* __restrict__ Vt, bf16* __restrict__ Og) {
  __shared__ bf16  Plds[3][64][32];   // waves 1-3 O^T partials (bf16)
  __shared__ float Mlds[4][64];
  __shared__ float Slds[4][64];
  const int tid = threadIdx.x;
  const int wv  = tid >> 6;          // split-K group 0..3
  const int l   = tid & 63;
  const int l31 = l & 31;
  const int hi  = l >> 5;
  const int h   = blockIdx.x & 15;
  const int i   = 127 - (int)(blockIdx.x >> 4);  // big tiles dispatch first
  const int q0  = i * 32;
  const int hc  = h * HDM;
  const int tlast = i >> 1;
  const int qg  = q0 + l31;
  constexpr float C = 0.18033688011112042f;  // 0.125 * log2(e)

  // Q B-frags: lane holds Q[qg][hc + ks*16 + hi*8 ..+8)
  bf16x8 qf[4];
#pragma unroll
  for (int ks = 0; ks < 4; ++ks)
    qf[ks] = *(const bf16x8*)(Qg + (size_t)qg * DIM + hc + ks * 16 + hi * 8);

  f32x16 ot0 = {}, ot1 = {};          // O^T: d = (r&3)+8*(r>>2)+4*hi (+32)
  float m2 = -3.0e38f, sum_ = 0.f;

#pragma unroll 1
  for (int t = wv; t <= tlast; t += 4) {
    const int kv0 = t * 64;
    bf16x8 kf0[4], kf1[4];
#pragma unroll
    for (int ks = 0; ks < 4; ++ks) {
      kf0[ks] = *(const bf16x8*)(Kg + (size_t)(kv0 + l31) * DIM + hc + ks * 16 + hi * 8);
      kf1[ks] = *(const bf16x8*)(Kg + (size_t)(kv0 + 32 + l31) * DIM + hc + ks * 16 + hi * 8);
    }
    f32x16 s0 = {}, s1 = {};
#pragma unroll
    for (int ks = 0; ks < 4; ++ks) {
      s0 = __builtin_amdgcn_mfma_f32_32x32x16_bf16(kf0[ks], qf[ks], s0, 0, 0, 0);
      s1 = __builtin_amdgcn_mfma_f32_32x32x16_bf16(kf1[ks], qf[ks], s1, 0, 0, 0);
    }
    bf16x8 vf0[4], vf1[4];
#pragma unroll
    for (int k2 = 0; k2 < 4; ++k2) {
      vf0[k2] = *(const bf16x8*)(Vt + (size_t)(hc + l31) * SEQ + kv0 + k2 * 16 + hi * 8);
      vf1[k2] = *(const bf16x8*)(Vt + (size_t)(hc + 32 + l31) * SEQ + kv0 + k2 * 16 + hi * 8);
    }
    if (t == tlast) {
#pragma unroll
      for (int r = 0; r < 16; ++r) {
        const int kp = (r & 3) + 8 * (r >> 2) + 4 * hi;
        s0[r] = (kv0 + kp      > qg) ? -1.0e30f : s0[r] * C;
        s1[r] = (kv0 + 32 + kp > qg) ? -1.0e30f : s1[r] * C;
      }
    } else {
#pragma unroll
      for (int r = 0; r < 16; ++r) { s0[r] *= C; s1[r] *= C; }
    }
    // row max: depth-5 tree + 1 partner exchange
    float tm[8];
#pragma unroll
    for (int r = 0; r < 8; ++r)
      tm[r] = fmaxf(fmaxf(s0[r], s0[r + 8]), fmaxf(s1[r], s1[r + 8]));
#pragma unroll
    for (int d = 4; d >= 1; d >>= 1)
#pragma unroll
      for (int r = 0; r < d; ++r) tm[r] = fmaxf(tm[r], tm[r + d]);
    const float pm = fmaxf(tm[0], __shfl_xor(tm[0], 32));
    // T13 defer-max: only rescale when some lane's tile-max exceeds m2+8.
    if (!__all(pm <= m2 + 8.0f)) {
      const float mn = fmaxf(m2, pm);
      const float al = __builtin_exp2f(m2 - mn);
      m2 = mn;
      sum_ *= al;
#pragma unroll
      for (int r = 0; r < 16; ++r) { ot0[r] *= al; ot1[r] *= al; }
    }
    float rs = 0.f;
#pragma unroll
    for (int r = 0; r < 16; ++r) {
      s0[r] = __builtin_exp2f(s0[r] - m2);
      s1[r] = __builtin_exp2f(s1[r] - m2);
      rs += s0[r] + s1[r];
    }
    sum_ += rs;
    // P^T B-frags via packed half-exchange with lane^32
#pragma unroll
    for (int sub = 0; sub < 2; ++sub) {
#pragma unroll
      for (int hf = 0; hf < 2; ++hf) {
        const int rb = hf * 8;
        float v0, v1, v2, v3, v4, v5, v6, v7;
        if (sub == 0) {
          v0 = s0[rb+0]; v1 = s0[rb+1]; v2 = s0[rb+2]; v3 = s0[rb+3];
          v4 = s0[rb+4]; v5 = s0[rb+5]; v6 = s0[rb+6]; v7 = s0[rb+7];
        } else {
          v0 = s1[rb+0]; v1 = s1[rb+1]; v2 = s1[rb+2]; v3 = s1[rb+3];
          v4 = s1[rb+4]; v5 = s1[rb+5]; v6 = s1[rb+6]; v7 = s1[rb+7];
        }
        const unsigned w0 = pack2(v0, v1), w1 = pack2(v2, v3);
        const unsigned w2 = pack2(v4, v5), w3 = pack2(v6, v7);
        const unsigned y0 = __shfl_xor((int)w0, 32), y1 = __shfl_xor((int)w1, 32);
        const unsigned y2 = __shfl_xor((int)w2, 32), y3 = __shfl_xor((int)w3, 32);
        u32x4 fu;
        fu[0] = hi ? y2 : w0;
        fu[1] = hi ? y3 : w1;
        fu[2] = hi ? w2 : y0;
        fu[3] = hi ? w3 : y1;
        const bf16x8 pb = __builtin_bit_cast(bf16x8, fu);
        const int k2 = sub * 2 + hf;
        ot0 = __builtin_amdgcn_mfma_f32_32x32x16_bf16(k2 == 0 ? vf0[0] : k2 == 1 ? vf0[1] : k2 == 2 ? vf0[2] : vf0[3], pb, ot0, 0, 0, 0);
        ot1 = __builtin_amdgcn_mfma_f32_32x32x16_bf16(k2 == 0 ? vf1[0] : k2 == 1 ? vf1[1] : k2 == 2 ? vf1[2] : vf1[3], pb, ot1, 0, 0, 0);
      }
    }
  }

  // spill partials
  Mlds[wv][l] = m2;
  Slds[wv][l] = sum_;
  if (wv) {
#pragma unroll
    for (int r = 0; r < 16; ++r) {
      Plds[wv - 1][l][r]      = (bf16)ot0[r];
      Plds[wv - 1][l][r + 16] = (bf16)ot1[r];
    }
  }
  __syncthreads();
  if (wv) return;

  // flash combine (wave 0)
  float mstar = m2;
#pragma unroll
  for (int w = 1; w < 4; ++w) mstar = fmaxf(mstar, Mlds[w][l]);
  float alw[4];
  alw[0] = __builtin_exp2f(m2 - mstar);
#pragma unroll
  for (int w = 1; w < 4; ++w) alw[w] = __builtin_exp2f(Mlds[w][l] - mstar);
  float den = 0.f;
#pragma unroll
  for (int w = 0; w < 4; ++w)
    den += (Slds[w][l] + Slds[w][l ^ 32]) * alw[w];
  float num0[16], num1[16];
#pragma unroll
  for (int r = 0; r < 16; ++r) { num0[r] = ot0[r] * alw[0]; num1[r] = ot1[r] * alw[0]; }
#pragma unroll
  for (int w = 1; w < 4; ++w) {
    bf16x8 p0 = *(const bf16x8*)(&Plds[w - 1][l][0]);
    bf16x8 p1 = *(const bf16x8*)(&Plds[w - 1][l][8]);
    bf16x8 p2 = *(const bf16x8*)(&Plds[w - 1][l][16]);
    bf16x8 p3 = *(const bf16x8*)(&Plds[w - 1][l][24]);
#pragma unroll
    for (int e = 0; e < 8; ++e) {
      num0[e]     += (float)p0[e] * alw[w];
      num0[e + 8] += (float)p1[e] * alw[w];
      num1[e]     += (float)p2[e] * alw[w];
      num1[e + 8] += (float)p3[e] * alw[w];
    }
  }
  const float inv = 1.0f / den;
#pragma unroll
  for (int g = 0; g < 4; ++g) {
    bf16x4 o0, o1;
#pragma unroll
    for (int e = 0; e < 4; ++e) {
      o0[e] = (bf16)(num0[g * 4 + e] * inv);
      o1[e] = (bf16)(num1[g * 4 + e] * inv);
    }
    *(bf16x4*)(Og + (size_t)qg * DIM + hc + g * 8 + hi * 4)      = o0;
    *(bf16x4*)(Og + (size_t)qg * DIM + hc + 32 + g * 8 + hi * 4) = o1;
  }
}

extern "C" void kernel_launch(void* const* d_in, const int* in_sizes, int n_in,
                              void* d_out, int out_size, void* d_ws, size_t ws_size,
                              hipStream_t stream) {
  const float* x  = (const float*)d_in[0];
  const float* Wq = (const float*)d_in[1];
  const float* Wk = (const float*)d_in[2];
  const float* Wv = (const float*)d_in[3];
  const float* Wo = (const float*)d_in[4];
  float* out = (float*)d_out;

  // ws (bf16, 48MB): xb 8MB | Wq..Wo 2MB each | Q,K,V 8MB each
  // aliases: Vt <- xb (xb dead after QKV gemm); At <- Vs (Vs dead after transpose)
  bf16* xb  = (bf16*)d_ws;
  bf16* wqb = xb  + (size_t)SEQ * DIM;
  bf16* wkb = wqb + (size_t)DIM * DIM;
  bf16* wvb = wkb + (size_t)DIM * DIM;
  bf16* wob = wvb + (size_t)DIM * DIM;
  bf16* Qs  = wob + (size_t)DIM * DIM;
  bf16* Ks  = Qs  + (size_t)SEQ * DIM;
  bf16* Vs  = Ks  + (size_t)SEQ * DIM;
  bf16* Vt  = xb;   // [DIM][SEQ]
  bf16* At  = Vs;

  cvt5<<<dim3((SEQ * DIM) / (256 * 8), 5), 256, 0, stream>>>(
      x, Wq, Wk, Wv, Wo, xb, wqb, wkb, wvb, wob);

  gemm_xwt<bf16, true><<<dim3(DIM / 128, SEQ / 128, 3), 256, 0, stream>>>(
      xb, wqb, wkb, wvb, Qs, Ks, Vs);

  transpose_v<<<dim3(SEQ / 64, DIM / 64), 256, 0, stream>>>(Vs, Vt);

  attn_fwd<<<dim3(128 * NH), 256, 0, stream>>>(Qs, Ks, Vt, At);

  gemm_xwt<float, false><<<dim3(DIM / 128, SEQ / 128), 256, 0, stream>>>(
      At, wob, nullptr, nullptr, out, nullptr, nullptr);
}

// Round 9
// 200.636 us; speedup vs baseline: 2.3812x; 1.0264x over previous
//
#include <hip/hip_runtime.h>
#include <hip/hip_bf16.h>
#include <stdint.h>

// B=1, S=4096, D=1024, H=16, HD=64. I/O = float32; internal compute bf16 MFMA.
constexpr int SEQ  = 4096;
constexpr int DIM  = 1024;
constexpr int NH   = 16;
constexpr int HDM  = 64;

typedef __bf16 bf16;
typedef __attribute__((ext_vector_type(4)))  float  f32x4;
typedef __attribute__((ext_vector_type(16))) float  f32x16;
typedef __attribute__((ext_vector_type(8)))  __bf16 bf16x8;
typedef __attribute__((ext_vector_type(4)))  __bf16 bf16x4;
typedef __attribute__((ext_vector_type(4)))  unsigned u32x4;

__device__ __forceinline__ void gload_lds16(const bf16* g, bf16* l) {
  __builtin_amdgcn_global_load_lds(
      (const __attribute__((address_space(1))) unsigned int*)g,
      (__attribute__((address_space(3))) unsigned int*)l, 16, 0, 0);
}

__device__ __forceinline__ unsigned pack2(float lo, float hi) {
  unsigned short a = __builtin_bit_cast(unsigned short, (bf16)lo);
  unsigned short b = __builtin_bit_cast(unsigned short, (bf16)hi);
  return ((unsigned)b << 16) | a;
}

// f32 -> bf16 for x + the 4 weight matrices. blockIdx.y selects tensor.
__global__ void cvt5(const float* __restrict__ x,  const float* __restrict__ wq,
                     const float* __restrict__ wk, const float* __restrict__ wv,
                     const float* __restrict__ wo,
                     bf16* __restrict__ xb,  bf16* __restrict__ wqb,
                     bf16* __restrict__ wkb, bf16* __restrict__ wvb,
                     bf16* __restrict__ wob) {
  const float* in; bf16* out; int n;
  switch (blockIdx.y) {
    case 0:  in = x;  out = xb;  n = SEQ * DIM; break;
    case 1:  in = wq; out = wqb; n = DIM * DIM; break;
    case 2:  in = wk; out = wkb; n = DIM * DIM; break;
    case 3:  in = wv; out = wvb; n = DIM * DIM; break;
    default: in = wo; out = wob; n = DIM * DIM; break;
  }
  const int i = (blockIdx.x * blockDim.x + threadIdx.x) * 8;
  if (i >= n) return;
  f32x4 a = *(const f32x4*)(in + i);
  f32x4 b = *(const f32x4*)(in + i + 4);
  bf16x8 o;
#pragma unroll
  for (int j = 0; j < 4; ++j) { o[j] = (bf16)a[j]; o[j + 4] = (bf16)b[j]; }
  *(bf16x8*)(out + i) = o;
}

// ---------------- GEMM: C = (A[rows][1024] * W[1024][1024]^T) * sc ----------
// QKV=true: z picks W/out; z==0 (Q) folds the attention scale 0.125*log2(e).
template <typename OutT, bool QKV>
__global__ __launch_bounds__(256, 2)
void gemm_xwt(const bf16* __restrict__ A,
              const bf16* __restrict__ W0, const bf16* __restrict__ W1,
              const bf16* __restrict__ W2,
              OutT* __restrict__ C0, OutT* __restrict__ C1, OutT* __restrict__ C2) {
  const bf16* W;
  OutT* C;
  float sc = 1.0f;
  if (QKV) {
    const int z = blockIdx.z;
    W = (z == 0) ? W0 : (z == 1) ? W1 : W2;
    C = (z == 0) ? C0 : (z == 1) ? C1 : C2;
    if (z == 0) sc = 0.18033688011112042f;  // 0.125 * log2(e)
  } else {
    W = W0; C = C0;
  }
  __shared__ bf16 As[128 * 32];
  __shared__ bf16 Bs[128 * 32];
  const int tid = threadIdx.x;
  const int w   = tid >> 6;
  const int l   = tid & 63;
  const int l15 = l & 15, lhi = l >> 4;
  const int wr  = w >> 1, wc = w & 1;
  const int row0 = blockIdx.y * 128;
  const int col0 = blockIdx.x * 128;

  f32x4 acc[4][4] = {};

  const int srow = w * 32 + (l >> 2);
  const int scol = (l & 3) * 8;
  const bf16* gA = A + (size_t)(row0 + srow) * DIM + scol;
  const bf16* gB = W + (size_t)(col0 + srow) * DIM + scol;
  bf16* lA = As + srow * 32 + scol;
  bf16* lB = Bs + srow * 32 + scol;

  for (int k0 = 0; k0 < DIM; k0 += 32) {
    __syncthreads();
    gload_lds16(gA + k0,            lA);
    gload_lds16(gA + k0 + 16 * DIM, lA + 16 * 32);
    gload_lds16(gB + k0,            lB);
    gload_lds16(gB + k0 + 16 * DIM, lB + 16 * 32);
    __syncthreads();
    bf16x8 af[4], bf_[4];
#pragma unroll
    for (int m = 0; m < 4; ++m)
      af[m] = *(const bf16x8*)(As + (wr * 64 + m * 16 + l15) * 32 + lhi * 8);
#pragma unroll
    for (int n = 0; n < 4; ++n)
      bf_[n] = *(const bf16x8*)(Bs + (wc * 64 + n * 16 + l15) * 32 + lhi * 8);
#pragma unroll
    for (int m = 0; m < 4; ++m)
#pragma unroll
      for (int n = 0; n < 4; ++n)
        acc[m][n] = __builtin_amdgcn_mfma_f32_16x16x32_bf16(af[m], bf_[n], acc[m][n], 0, 0, 0);
  }

#pragma unroll
  for (int m = 0; m < 4; ++m)
#pragma unroll
    for (int n = 0; n < 4; ++n)
#pragma unroll
      for (int r = 0; r < 4; ++r) {
        const int row = row0 + wr * 64 + m * 16 + lhi * 4 + r;
        const int col = col0 + wc * 64 + n * 16 + l15;
        C[(size_t)row * DIM + col] = (OutT)(acc[m][n][r] * sc);
      }
}

// --------------- V transpose: Vt[d][s] = Vs[s][d]  (once) -------------------
__global__ __launch_bounds__(256)
void transpose_v(const bf16* __restrict__ Vs, bf16* __restrict__ Vt) {
  __shared__ bf16 t[64][72];
  const int st = blockIdx.x * 64;
  const int dt = blockIdx.y * 64;
  const int tid = threadIdx.x;
  const int r  = tid >> 2;
  const int c0 = (tid & 3) * 16;
  bf16x8 a = *(const bf16x8*)(Vs + (size_t)(st + r) * DIM + dt + c0);
  bf16x8 b = *(const bf16x8*)(Vs + (size_t)(st + r) * DIM + dt + c0 + 8);
#pragma unroll
  for (int j = 0; j < 8; ++j) { t[r][c0 + j] = a[j]; t[r][c0 + 8 + j] = b[j]; }
  __syncthreads();
  const int d  = tid >> 2;
  const int s0 = (tid & 3) * 16;
  bf16x8 o1, o2;
#pragma unroll
  for (int j = 0; j < 8; ++j) { o1[j] = t[s0 + j][d]; o2[j] = t[s0 + 8 + j][d]; }
  bf16* dst = Vt + (size_t)(dt + d) * SEQ + st + s0;
  *(bf16x8*)(dst)     = o1;
  *(bf16x8*)(dst + 8) = o2;
}

// ------- Causal flash attention, swapped-operand 32x32, 4-way split-K -------
// Block = 4 waves, one 32-row q-tile. Wave g does KV tiles t = g, g+4, ...
// Q pre-scaled by 0.125*log2e (folded into Q-GEMM). Cross-half exchange via
// __shfl_xor(...,32) (proven r6 primitive; permlane asm was the r7/r8 bug).
// K single-buffer prefetch hides K latency under softmax+PV.
__global__ __launch_bounds__(256, 2)
void attn_fwd(const bf16* __restrict__ Qg, const bf16* __restrict__ Kg,
              const bf16* __restrict__ Vt, bf16* __restrict__ Og) {
  __shared__ bf16  Plds[3][64][32];   // waves 1-3 O^T partials (bf16)
  __shared__ float Mlds[4][64];
  __shared__ float Slds[4][64];
  const int tid = threadIdx.x;
  const int wv  = tid >> 6;          // split-K group 0..3
  const int l   = tid & 63;
  const int l31 = l & 31;
  const int hi  = l >> 5;
  const int h   = blockIdx.x & 15;
  const int i   = 127 - (int)(blockIdx.x >> 4);  // big tiles dispatch first
  const int q0  = i * 32;
  const int hc  = h * HDM;
  const int tlast = i >> 1;
  const int qg  = q0 + l31;

  // Q B-frags: lane holds Q[qg][hc + ks*16 + hi*8 ..+8)   (pre-scaled)
  bf16x8 qf[4];
#pragma unroll
  for (int ks = 0; ks < 4; ++ks)
    qf[ks] = *(const bf16x8*)(Qg + (size_t)qg * DIM + hc + ks * 16 + hi * 8);

  f32x16 ot0 = {}, ot1 = {};          // O^T: d = (r&3)+8*(r>>2)+4*hi (+32)
  float m2 = -3.0e38f, sum_ = 0.f;

  if (wv <= tlast) {
    const bf16* Kbase = Kg + (size_t)l31 * DIM + hc + hi * 8;
    const bf16* Vbase = Vt + (size_t)(hc + l31) * SEQ + hi * 8;
    bf16x8 kf0[4], kf1[4];
    {
      const bf16* kp = Kbase + (size_t)(wv * 64) * DIM;
#pragma unroll
      for (int ks = 0; ks < 4; ++ks) {
        kf0[ks] = *(const bf16x8*)(kp + ks * 16);
        kf1[ks] = *(const bf16x8*)(kp + 32 * DIM + ks * 16);
      }
    }
#pragma unroll 1
    for (int t = wv; t <= tlast; t += 4) {
      const int kv0 = t * 64;
      // S^T = K Q^T
      f32x16 s0 = {}, s1 = {};
#pragma unroll
      for (int ks = 0; ks < 4; ++ks) {
        s0 = __builtin_amdgcn_mfma_f32_32x32x16_bf16(kf0[ks], qf[ks], s0, 0, 0, 0);
        s1 = __builtin_amdgcn_mfma_f32_32x32x16_bf16(kf1[ks], qf[ks], s1, 0, 0, 0);
      }
      // V^T frags for THIS tile (issued before K prefetch)
      bf16x8 vf0[4], vf1[4];
#pragma unroll
      for (int k2 = 0; k2 < 4; ++k2) {
        vf0[k2] = *(const bf16x8*)(Vbase + kv0 + k2 * 16);
        vf1[k2] = *(const bf16x8*)(Vbase + 32 * SEQ + kv0 + k2 * 16);
      }
      // K prefetch for t+4 into the same regs (QK above already consumed them)
      if (t + 4 <= tlast) {
        const bf16* kp = Kbase + (size_t)((t + 4) * 64) * DIM;
#pragma unroll
        for (int ks = 0; ks < 4; ++ks) {
          kf0[ks] = *(const bf16x8*)(kp + ks * 16);
          kf1[ks] = *(const bf16x8*)(kp + 32 * DIM + ks * 16);
        }
      }
      // causal mask (diagonal tile only; scale already folded into Q)
      if (t == tlast) {
#pragma unroll
        for (int r = 0; r < 16; ++r) {
          const int kp = (r & 3) + 8 * (r >> 2) + 4 * hi;
          if (kv0 + kp      > qg) s0[r] = -1.0e30f;
          if (kv0 + 32 + kp > qg) s1[r] = -1.0e30f;
        }
      }
      // row max: depth-5 tree + one cross-half shuffle
      float tm[8];
#pragma unroll
      for (int r = 0; r < 8; ++r)
        tm[r] = fmaxf(fmaxf(s0[r], s0[r + 8]), fmaxf(s1[r], s1[r + 8]));
#pragma unroll
      for (int d = 4; d >= 1; d >>= 1)
#pragma unroll
        for (int r = 0; r < d; ++r) tm[r] = fmaxf(tm[r], tm[r + d]);
      const float pm = fmaxf(tm[0], __shfl_xor(tm[0], 32));
      // T13 defer-max: rescale only when needed (P bounded by 2^8)
      if (!__all(pm <= m2 + 8.0f)) {
        const float mn = fmaxf(m2, pm);
        const float al = __builtin_exp2f(m2 - mn);
        m2 = mn;
        sum_ *= al;
#pragma unroll
        for (int r = 0; r < 16; ++r) { ot0[r] *= al; ot1[r] *= al; }
      }
      float rs = 0.f;
#pragma unroll
      for (int r = 0; r < 16; ++r) {
        s0[r] = __builtin_exp2f(s0[r] - m2);
        s1[r] = __builtin_exp2f(s1[r] - m2);
        rs += s0[r] + s1[r];
      }
      sum_ += rs;
      // P^T B-frags. Needed per lane: fu = [hi? partner_w2 : w0,
      //   hi? partner_w3 : w1, hi? w2 : partner_w0, hi? w3 : partner_w1].
      // Each lane SENDS what its partner needs (hi sends w0/w1, lo sends
      // w2/w3); one shfl_xor(32) per channel returns the partner's word.
#pragma unroll
      for (int sub = 0; sub < 2; ++sub) {
#pragma unroll
        for (int hf = 0; hf < 2; ++hf) {
          const int rb = hf * 8;
          float v0, v1, v2, v3, v4, v5, v6, v7;
          if (sub == 0) {
            v0 = s0[rb+0]; v1 = s0[rb+1]; v2 = s0[rb+2]; v3 = s0[rb+3];
            v4 = s0[rb+4]; v5 = s0[rb+5]; v6 = s0[rb+6]; v7 = s0[rb+7];
          } else {
            v0 = s1[rb+0]; v1 = s1[rb+1]; v2 = s1[rb+2]; v3 = s1[rb+3];
            v4 = s1[rb+4]; v5 = s1[rb+5]; v6 = s1[rb+6]; v7 = s1[rb+7];
          }
          const unsigned w0 = pack2(v0, v1), w1 = pack2(v2, v3);
          const unsigned w2 = pack2(v4, v5), w3 = pack2(v6, v7);
          const unsigned sa = hi ? w0 : w2;
          const unsigned sb = hi ? w1 : w3;
          const unsigned ra  = (unsigned)__shfl_xor((int)sa, 32);
          const unsigned rb_ = (unsigned)__shfl_xor((int)sb, 32);
          u32x4 fu;
          fu[0] = hi ? ra  : w0;
          fu[1] = hi ? rb_ : w1;
          fu[2] = hi ? w2  : ra;
          fu[3] = hi ? w3  : rb_;
          const bf16x8 pb = __builtin_bit_cast(bf16x8, fu);
          const int k2 = sub * 2 + hf;
          ot0 = __builtin_amdgcn_mfma_f32_32x32x16_bf16(
              k2 == 0 ? vf0[0] : k2 == 1 ? vf0[1] : k2 == 2 ? vf0[2] : vf0[3],
              pb, ot0, 0, 0, 0);
          ot1 = __builtin_amdgcn_mfma_f32_32x32x16_bf16(
              k2 == 0 ? vf1[0] : k2 == 1 ? vf1[1] : k2 == 2 ? vf1[2] : vf1[3],
              pb, ot1, 0, 0, 0);
        }
      }
    }
  }

  // spill partials
  Mlds[wv][l] = m2;
  Slds[wv][l] = sum_;
  if (wv) {
#pragma unroll
    for (int r = 0; r < 16; ++r) {
      Plds[wv - 1][l][r]      = (bf16)ot0[r];
      Plds[wv - 1][l][r + 16] = (bf16)ot1[r];
    }
  }
  __syncthreads();
  if (wv) return;

  // flash combine (wave 0)
  float mstar = m2;
#pragma unroll
  for (int w = 1; w < 4; ++w) mstar = fmaxf(mstar, Mlds[w][l]);
  float alw[4];
  alw[0] = __builtin_exp2f(m2 - mstar);
#pragma unroll
  for (int w = 1; w < 4; ++w) alw[w] = __builtin_exp2f(Mlds[w][l] - mstar);
  float den = 0.f;
#pragma unroll
  for (int w = 0; w < 4; ++w)
    den += (Slds[w][l] + Slds[w][l ^ 32]) * alw[w];
  float num0[16], num1[16];
#pragma unroll
  for (int r = 0; r < 16; ++r) { num0[r] = ot0[r] * alw[0]; num1[r] = ot1[r] * alw[0]; }
#pragma unroll
  for (int w = 1; w < 4; ++w) {
    bf16x8 p0 = *(const bf16x8*)(&Plds[w - 1][l][0]);
    bf16x8 p1 = *(const bf16x8*)(&Plds[w - 1][l][8]);
    bf16x8 p2 = *(const bf16x8*)(&Plds[w - 1][l][16]);
    bf16x8 p3 = *(const bf16x8*)(&Plds[w - 1][l][24]);
#pragma unroll
    for (int e = 0; e < 8; ++e) {
      num0[e]     += (float)p0[e] * alw[w];
      num0[e + 8] += (float)p1[e] * alw[w];
      num1[e]     += (float)p2[e] * alw[w];
      num1[e + 8] += (float)p3[e] * alw[w];
    }
  }
  const float inv = 1.0f / den;
#pragma unroll
  for (int g = 0; g < 4; ++g) {
    bf16x4 o0, o1;
#pragma unroll
    for (int e = 0; e < 4; ++e) {
      o0[e] = (bf16)(num0[g * 4 + e] * inv);
      o1[e] = (bf16)(num1[g * 4 + e] * inv);
    }
    *(bf16x4*)(Og + (size_t)qg * DIM + hc + g * 8 + hi * 4)      = o0;
    *(bf16x4*)(Og + (size_t)qg * DIM + hc + 32 + g * 8 + hi * 4) = o1;
  }
}

extern "C" void kernel_launch(void* const* d_in, const int* in_sizes, int n_in,
                              void* d_out, int out_size, void* d_ws, size_t ws_size,
                              hipStream_t stream) {
  const float* x  = (const float*)d_in[0];
  const float* Wq = (const float*)d_in[1];
  const float* Wk = (const float*)d_in[2];
  const float* Wv = (const float*)d_in[3];
  const float* Wo = (const float*)d_in[4];
  float* out = (float*)d_out;

  // ws (bf16, 48MB): xb 8MB | Wq..Wo 2MB each | Q,K,V 8MB each
  // aliases: Vt <- xb (xb dead after QKV gemm); At <- Vs (Vs dead after transpose)
  bf16* xb  = (bf16*)d_ws;
  bf16* wqb = xb  + (size_t)SEQ * DIM;
  bf16* wkb = wqb + (size_t)DIM * DIM;
  bf16* wvb = wkb + (size_t)DIM * DIM;
  bf16* wob = wvb + (size_t)DIM * DIM;
  bf16* Qs  = wob + (size_t)DIM * DIM;
  bf16* Ks  = Qs  + (size_t)SEQ * DIM;
  bf16* Vs  = Ks  + (size_t)SEQ * DIM;
  bf16* Vt  = xb;   // [DIM][SEQ]
  bf16* At  = Vs;

  cvt5<<<dim3((SEQ * DIM) / (256 * 8), 5), 256, 0, stream>>>(
      x, Wq, Wk, Wv, Wo, xb, wqb, wkb, wvb, wob);

  gemm_xwt<bf16, true><<<dim3(DIM / 128, SEQ / 128, 3), 256, 0, stream>>>(
      xb, wqb, wkb, wvb, Qs, Ks, Vs);

  transpose_v<<<dim3(SEQ / 64, DIM / 64), 256, 0, stream>>>(Vs, Vt);

  attn_fwd<<<dim3(128 * NH), 256, 0, stream>>>(Qs, Ks, Vt, At);

  gemm_xwt<float, false><<<dim3(DIM / 128, SEQ / 128), 256, 0, stream>>>(
      At, wob, nullptr, nullptr, out, nullptr, nullptr);
}